// Round 4
// baseline (378.783 us; speedup 1.0000x reference)
//
#include <hip/hip_runtime.h>
#include <cstdint>
#include <cstddef>

// R10: R8's kernel (verified 104 us dispatch) with ONE structural change:
// pack 4 batches = 4 waves per 256-thread workgroup. R8/R9 showed occupancy
// is pinned at ~18-21% with 1-wave workgroups regardless of VGPR 100-132
// (R9's VGPR=132 tier-crossing halved it -> reverted greedy to R8 verbatim).
// The limiter is per-CU workgroup slots, not registers: 64-thread WGs leave
// ~6 waves/CU resident. 4 waves/WG raises resident waves toward the VGPR
// tier cap (16/CU at VGPR<=128), overlapping the dependent-chain stalls
// (sinkhorn LDS round-trip + fma chain + IEEE divide; greedy scan chains)
// that dominate at 1.5 waves/SIMD. Math is byte-for-byte R8: bitwise
// identical scores and greedy selections. Each wave gets a private
// bufU/bufV[64] LDS slice; DS ops are in-order within a wave -> no barriers.
// amdgpu_waves_per_eu(4) caps VGPR at 128 (guards R9's tier cliff; R8's
// natural usage was 104 so no remat pressure).

typedef float f2 __attribute__((ext_vector_type(2)));

__device__ __forceinline__ f2 fma2(f2 a, f2 b, f2 c) {
#if defined(__has_builtin) && __has_builtin(__builtin_elementwise_fma)
    return __builtin_elementwise_fma(a, b, c);
#else
    f2 r; r.x = __builtin_fmaf(a.x, b.x, c.x); r.y = __builtin_fmaf(a.y, b.y, c.y);
    return r;
#endif
}

__global__ void __launch_bounds__(256)
__attribute__((amdgpu_waves_per_eu(4)))
sinkhorn_perm_kernel(const float* __restrict__ logits,
                     const float* __restrict__ ptemp,
                     float* __restrict__ out,
                     int B)
{
    __shared__ __attribute__((aligned(16))) float bufU[4][64];
    __shared__ __attribute__((aligned(16))) float bufV[4][64];

    const int wave = threadIdx.x >> 6;
    const int lane = threadIdx.x & 63;
    const int b    = blockIdx.x * 4 + wave;
    if (b >= B) return;                      // whole-wave exit; no barriers used

    const float* base = logits + (size_t)b * 4096;

    const float T    = ptemp[0] + 1e-6f;
    const float invT = 1.0f / T;          // IEEE divide (one-time)

    // ---- load row `lane`, scale by invT; pairs (4t,4t+1),(4t+2,4t+3) --
    f2 row2[32];
    {
        const float4* rp = (const float4*)(base + lane * 64);
        #pragma unroll
        for (int t = 0; t < 16; ++t) {
            float4 q = rp[t];
            row2[2*t+0].x = __fmul_rn(q.x, invT);
            row2[2*t+0].y = __fmul_rn(q.y, invT);
            row2[2*t+1].x = __fmul_rn(q.z, invT);
            row2[2*t+1].y = __fmul_rn(q.w, invT);
        }
    }

    // ---- global max over the 64x64 tile -------------------------------
    float mx = row2[0].x;
    #pragma unroll
    for (int i = 0; i < 32; ++i) { mx = fmaxf(mx, row2[i].x); mx = fmaxf(mx, row2[i].y); }
    #pragma unroll
    for (int w = 1; w <= 32; w <<= 1)
        mx = fmaxf(mx, __shfl_xor(mx, w, 64));

    // ---- x0 row copy: exp(scaled - mx) --------------------------------
    #pragma unroll
    for (int i = 0; i < 32; ++i) {
        row2[i].x = __expf(__fsub_rn(row2[i].x, mx));
        row2[i].y = __expf(__fsub_rn(row2[i].y, mx));
    }

    // ---- x0 column copy: coalesced global re-read, identical op seq ---
    float col[64];
    #pragma unroll
    for (int i = 0; i < 64; ++i) {
        float raw = base[i * 64 + lane];
        col[i] = __expf(__fsub_rn(__fmul_rn(raw, invT), mx));
    }

    // ---- sinkhorn in diag(u) * X0 * diag(v) form ----------------------
    // Broadcast of v (row phase) / u (col phase) via this wave's private
    // LDS slice: wave-uniform ds_read_b128 is a hardware broadcast.
    // Pairing and summation order identical to R6/R7/R8:
    // rs = (A0.x+A0.y)+(A1.x+A1.y).
    const float4* bu4 = (const float4*)&bufU[wave][0];
    const float4* bv4 = (const float4*)&bufV[wave][0];

    float u = 1.0f, v = 1.0f;
    for (int it = 0; it < 30; ++it) {
        // row phase: rs_i = row_i . v
        bufV[wave][lane] = v;
        f2 A0 = {0.f, 0.f}, A1 = {0.f, 0.f};
        #pragma unroll
        for (int t = 0; t < 16; ++t) {
            float4 q = bv4[t];
            f2 qa = { q.x, q.y };
            f2 qb = { q.z, q.w };
            A0 = fma2(row2[2*t+0], qa, A0);
            A1 = fma2(row2[2*t+1], qb, A1);
        }
        float rs = __fadd_rn(__fadd_rn(A0.x, A0.y), __fadd_rn(A1.x, A1.y));
        u = u / __fadd_rn(__fmul_rn(u, rs), 1e-8f);   // IEEE divide

        // col phase: cs_j = col_j . u  (updated u broadcast)
        bufU[wave][lane] = u;
        A0 = (f2){0.f, 0.f}; A1 = (f2){0.f, 0.f};
        #pragma unroll
        for (int t = 0; t < 16; ++t) {
            float4 q = bu4[t];
            f2 ca = { col[4*t+0], col[4*t+1] };
            f2 cb = { col[4*t+2], col[4*t+3] };
            f2 qa = { q.x, q.y };
            f2 qb = { q.z, q.w };
            A0 = fma2(ca, qa, A0);
            A1 = fma2(cb, qb, A1);
        }
        float cs = __fadd_rn(__fadd_rn(A0.x, A0.y), __fadd_rn(A1.x, A1.y));
        v = v / __fadd_rn(__fmul_rn(v, cs), 1e-8f);
    }

    // ---- final scores in BOTH layouts: s[i][j] = (x0[i][j] * u_i) * v_j
    // col layout (lane = col j): col[i] = (x0c[i] * bufU[i]) * v_own
    // bufU holds final u (last written in iteration 29's col phase).
    #pragma unroll
    for (int t = 0; t < 16; ++t) {
        float4 q = bu4[t];
        col[4*t+0] = __fmul_rn(__fmul_rn(col[4*t+0], q.x), v);
        col[4*t+1] = __fmul_rn(__fmul_rn(col[4*t+1], q.y), v);
        col[4*t+2] = __fmul_rn(__fmul_rn(col[4*t+2], q.z), v);
        col[4*t+3] = __fmul_rn(__fmul_rn(col[4*t+3], q.w), v);
    }
    // row layout (lane = row i): row2[j] = (x0r[j] * u_own) * bufV[j].
    // Same (x0*u)*v tree on bitwise-equal x0 and the same u_i / v_j bits =>
    // row/col score copies are bitwise identical.
    bufV[wave][lane] = v;   // final v (in-order DS within wave)
    #pragma unroll
    for (int t = 0; t < 16; ++t) {
        float4 q = bv4[t];
        row2[2*t+0].x = __fmul_rn(__fmul_rn(row2[2*t+0].x, u), q.x);
        row2[2*t+0].y = __fmul_rn(__fmul_rn(row2[2*t+0].y, u), q.y);
        row2[2*t+1].x = __fmul_rn(__fmul_rn(row2[2*t+1].x, u), q.z);
        row2[2*t+1].y = __fmul_rn(__fmul_rn(row2[2*t+1].y, u), q.w);
    }

    // ---- greedy unique argmax: parallel mutual-max retirement ----------
    // R8 verbatim. Total order: value desc, flat index asc — matches
    // jnp.argsort(-s) stable semantics. Masked scans use strict '>' over
    // ascending index => exact total-order argmax per row/col (all scores
    // are > 0, so masking to 0.0f never wins; bv init 0.0f).
    unsigned long long rowmask = ~0ull;   // wave-uniform (SGPR pair)
    unsigned long long colmask = ~0ull;
    int mycol  = 0;
    int rounds = 0;

    while (rowmask && rounds < 64) {
        ++rounds;

        // row side (lane = row i): best live column
        float rbv = 0.0f; int rbj = 0;
        #pragma unroll
        for (int j = 0; j < 64; ++j) {
            unsigned sm = ((colmask >> j) & 1ull) ? 0xFFFFFFFFu : 0u;
            float sv = (j & 1) ? row2[j >> 1].y : row2[j >> 1].x;
            float s  = __uint_as_float(__float_as_uint(sv) & sm);
            if (s > rbv) { rbv = s; rbj = j; }
        }

        // col side (lane = col j): best live row
        float cbv = 0.0f; int cbi = 0;
        #pragma unroll
        for (int i = 0; i < 64; ++i) {
            unsigned sm = ((rowmask >> i) & 1ull) ? 0xFFFFFFFFu : 0u;
            float s  = __uint_as_float(__float_as_uint(col[i]) & sm);
            if (s > cbv) { cbv = s; cbi = i; }
        }

        // mutual check: row i's candidate col c=rbj is mutual iff
        // colArg[c] == i; col j's candidate row r=cbi is mutual iff
        // rowArg[r] == j. (Candidates from masked scans are always live.)
        int gr = __builtin_amdgcn_ds_bpermute(rbj << 2, cbi); // colArg[rbj]
        int gc = __builtin_amdgcn_ds_bpermute(cbi << 2, rbj); // rowArg[cbi]
        bool aR = (rowmask >> lane) & 1ull;
        bool aC = (colmask >> lane) & 1ull;
        bool mr = aR && (gr == lane);
        bool mc = aC && (gc == lane);
        if (mr) mycol = rbj;
        rowmask &= ~__ballot(mr);
        colmask &= ~__ballot(mc);
    }

    // ---- write hard permutation row (lane i -> row i) -----------------
    float* orow = out + (size_t)b * 4096 + lane * 64;
    #pragma unroll
    for (int t = 0; t < 16; ++t) {
        float4 q;
        q.x = (4*t+0 == mycol) ? 1.0f : 0.0f;
        q.y = (4*t+1 == mycol) ? 1.0f : 0.0f;
        q.z = (4*t+2 == mycol) ? 1.0f : 0.0f;
        q.w = (4*t+3 == mycol) ? 1.0f : 0.0f;
        ((float4*)orow)[t] = q;
    }
}

extern "C" void kernel_launch(void* const* d_in, const int* in_sizes, int n_in,
                              void* d_out, int out_size, void* d_ws, size_t ws_size,
                              hipStream_t stream) {
    const float* logits = (const float*)d_in[0];
    const float* ptemp  = (const float*)d_in[1];
    float* out = (float*)d_out;
    const int B = in_sizes[0] / 4096;   // 64*64 elements per batch
    const int G = (B + 3) / 4;          // 4 batches (waves) per workgroup
    sinkhorn_perm_kernel<<<G, 256, 0, stream>>>(logits, ptemp, out, B);
}

// Round 5
// 188.225 us; speedup vs baseline: 2.0124x; 2.0124x over previous
//
#include <hip/hip_runtime.h>
#include <cstdint>
#include <cstddef>

// R11 = R10's structure (4 batches = 4 waves per 256-thread WG; verified to
// raise occupancy 18%->42.6%) with the VGPR cap REMOVED. R10's
// amdgpu_waves_per_eu(4) squeezed allocation to 64 VGPRs, spilling
// row2[32]+col[64] (~130 live floats) to scratch: FETCH_SIZE 33MB->458MB,
// WRITE_SIZE 66MB->187MB, VALUBusy 19%, 300us. Back to waves_per_eu(1),
// under which this exact per-wave code compiled to 104-116 VGPRs with zero
// scratch (R7/R8). At ~116 VGPRs the HW still fits 4 waves/SIMD (512-reg
// pool), so the occupancy win stands without the spills.
// Math is byte-for-byte R8 per wave: bitwise-identical scores and greedy
// selections. Private per-wave LDS slices; DS in-order within wave -> no
// barriers. B=4096 is divisible by 4 -> no partial workgroups.

typedef float f2 __attribute__((ext_vector_type(2)));

__device__ __forceinline__ f2 fma2(f2 a, f2 b, f2 c) {
#if defined(__has_builtin) && __has_builtin(__builtin_elementwise_fma)
    return __builtin_elementwise_fma(a, b, c);
#else
    f2 r; r.x = __builtin_fmaf(a.x, b.x, c.x); r.y = __builtin_fmaf(a.y, b.y, c.y);
    return r;
#endif
}

__global__ void __launch_bounds__(256)
__attribute__((amdgpu_waves_per_eu(1)))
sinkhorn_perm_kernel(const float* __restrict__ logits,
                     const float* __restrict__ ptemp,
                     float* __restrict__ out,
                     int B)
{
    __shared__ __attribute__((aligned(16))) float bufU[4][64];
    __shared__ __attribute__((aligned(16))) float bufV[4][64];

    const int wave = threadIdx.x >> 6;
    const int lane = threadIdx.x & 63;
    const int b    = blockIdx.x * 4 + wave;
    if (b >= B) return;                      // whole-wave exit; no barriers used

    const float* base = logits + (size_t)b * 4096;

    const float T    = ptemp[0] + 1e-6f;
    const float invT = 1.0f / T;          // IEEE divide (one-time)

    // ---- load row `lane`, scale by invT; pairs (4t,4t+1),(4t+2,4t+3) --
    f2 row2[32];
    {
        const float4* rp = (const float4*)(base + lane * 64);
        #pragma unroll
        for (int t = 0; t < 16; ++t) {
            float4 q = rp[t];
            row2[2*t+0].x = __fmul_rn(q.x, invT);
            row2[2*t+0].y = __fmul_rn(q.y, invT);
            row2[2*t+1].x = __fmul_rn(q.z, invT);
            row2[2*t+1].y = __fmul_rn(q.w, invT);
        }
    }

    // ---- global max over the 64x64 tile -------------------------------
    float mx = row2[0].x;
    #pragma unroll
    for (int i = 0; i < 32; ++i) { mx = fmaxf(mx, row2[i].x); mx = fmaxf(mx, row2[i].y); }
    #pragma unroll
    for (int w = 1; w <= 32; w <<= 1)
        mx = fmaxf(mx, __shfl_xor(mx, w, 64));

    // ---- x0 row copy: exp(scaled - mx) --------------------------------
    #pragma unroll
    for (int i = 0; i < 32; ++i) {
        row2[i].x = __expf(__fsub_rn(row2[i].x, mx));
        row2[i].y = __expf(__fsub_rn(row2[i].y, mx));
    }

    // ---- x0 column copy: coalesced global re-read, identical op seq ---
    float col[64];
    #pragma unroll
    for (int i = 0; i < 64; ++i) {
        float raw = base[i * 64 + lane];
        col[i] = __expf(__fsub_rn(__fmul_rn(raw, invT), mx));
    }

    // ---- sinkhorn in diag(u) * X0 * diag(v) form ----------------------
    // Broadcast of v (row phase) / u (col phase) via this wave's private
    // LDS slice: wave-uniform ds_read_b128 is a hardware broadcast.
    // Pairing and summation order identical to R6/R7/R8:
    // rs = (A0.x+A0.y)+(A1.x+A1.y).
    const float4* bu4 = (const float4*)&bufU[wave][0];
    const float4* bv4 = (const float4*)&bufV[wave][0];

    float u = 1.0f, v = 1.0f;
    for (int it = 0; it < 30; ++it) {
        // row phase: rs_i = row_i . v
        bufV[wave][lane] = v;
        f2 A0 = {0.f, 0.f}, A1 = {0.f, 0.f};
        #pragma unroll
        for (int t = 0; t < 16; ++t) {
            float4 q = bv4[t];
            f2 qa = { q.x, q.y };
            f2 qb = { q.z, q.w };
            A0 = fma2(row2[2*t+0], qa, A0);
            A1 = fma2(row2[2*t+1], qb, A1);
        }
        float rs = __fadd_rn(__fadd_rn(A0.x, A0.y), __fadd_rn(A1.x, A1.y));
        u = u / __fadd_rn(__fmul_rn(u, rs), 1e-8f);   // IEEE divide

        // col phase: cs_j = col_j . u  (updated u broadcast)
        bufU[wave][lane] = u;
        A0 = (f2){0.f, 0.f}; A1 = (f2){0.f, 0.f};
        #pragma unroll
        for (int t = 0; t < 16; ++t) {
            float4 q = bu4[t];
            f2 ca = { col[4*t+0], col[4*t+1] };
            f2 cb = { col[4*t+2], col[4*t+3] };
            f2 qa = { q.x, q.y };
            f2 qb = { q.z, q.w };
            A0 = fma2(ca, qa, A0);
            A1 = fma2(cb, qb, A1);
        }
        float cs = __fadd_rn(__fadd_rn(A0.x, A0.y), __fadd_rn(A1.x, A1.y));
        v = v / __fadd_rn(__fmul_rn(v, cs), 1e-8f);
    }

    // ---- final scores in BOTH layouts: s[i][j] = (x0[i][j] * u_i) * v_j
    // col layout (lane = col j): col[i] = (x0c[i] * bufU[i]) * v_own
    // bufU holds final u (last written in iteration 29's col phase).
    #pragma unroll
    for (int t = 0; t < 16; ++t) {
        float4 q = bu4[t];
        col[4*t+0] = __fmul_rn(__fmul_rn(col[4*t+0], q.x), v);
        col[4*t+1] = __fmul_rn(__fmul_rn(col[4*t+1], q.y), v);
        col[4*t+2] = __fmul_rn(__fmul_rn(col[4*t+2], q.z), v);
        col[4*t+3] = __fmul_rn(__fmul_rn(col[4*t+3], q.w), v);
    }
    // row layout (lane = row i): row2[j] = (x0r[j] * u_own) * bufV[j].
    // Same (x0*u)*v tree on bitwise-equal x0 and the same u_i / v_j bits =>
    // row/col score copies are bitwise identical.
    bufV[wave][lane] = v;   // final v (in-order DS within wave)
    #pragma unroll
    for (int t = 0; t < 16; ++t) {
        float4 q = bv4[t];
        row2[2*t+0].x = __fmul_rn(__fmul_rn(row2[2*t+0].x, u), q.x);
        row2[2*t+0].y = __fmul_rn(__fmul_rn(row2[2*t+0].y, u), q.y);
        row2[2*t+1].x = __fmul_rn(__fmul_rn(row2[2*t+1].x, u), q.z);
        row2[2*t+1].y = __fmul_rn(__fmul_rn(row2[2*t+1].y, u), q.w);
    }

    // ---- greedy unique argmax: parallel mutual-max retirement ----------
    // R8 verbatim. Total order: value desc, flat index asc — matches
    // jnp.argsort(-s) stable semantics. Masked scans use strict '>' over
    // ascending index => exact total-order argmax per row/col (all scores
    // are > 0, so masking to 0.0f never wins; bv init 0.0f).
    unsigned long long rowmask = ~0ull;   // wave-uniform (SGPR pair)
    unsigned long long colmask = ~0ull;
    int mycol  = 0;
    int rounds = 0;

    while (rowmask && rounds < 64) {
        ++rounds;

        // row side (lane = row i): best live column
        float rbv = 0.0f; int rbj = 0;
        #pragma unroll
        for (int j = 0; j < 64; ++j) {
            unsigned sm = ((colmask >> j) & 1ull) ? 0xFFFFFFFFu : 0u;
            float sv = (j & 1) ? row2[j >> 1].y : row2[j >> 1].x;
            float s  = __uint_as_float(__float_as_uint(sv) & sm);
            if (s > rbv) { rbv = s; rbj = j; }
        }

        // col side (lane = col j): best live row
        float cbv = 0.0f; int cbi = 0;
        #pragma unroll
        for (int i = 0; i < 64; ++i) {
            unsigned sm = ((rowmask >> i) & 1ull) ? 0xFFFFFFFFu : 0u;
            float s  = __uint_as_float(__float_as_uint(col[i]) & sm);
            if (s > cbv) { cbv = s; cbi = i; }
        }

        // mutual check: row i's candidate col c=rbj is mutual iff
        // colArg[c] == i; col j's candidate row r=cbi is mutual iff
        // rowArg[r] == j. (Candidates from masked scans are always live.)
        int gr = __builtin_amdgcn_ds_bpermute(rbj << 2, cbi); // colArg[rbj]
        int gc = __builtin_amdgcn_ds_bpermute(cbi << 2, rbj); // rowArg[cbi]
        bool aR = (rowmask >> lane) & 1ull;
        bool aC = (colmask >> lane) & 1ull;
        bool mr = aR && (gr == lane);
        bool mc = aC && (gc == lane);
        if (mr) mycol = rbj;
        rowmask &= ~__ballot(mr);
        colmask &= ~__ballot(mc);
    }

    // ---- write hard permutation row (lane i -> row i) -----------------
    float* orow = out + (size_t)b * 4096 + lane * 64;
    #pragma unroll
    for (int t = 0; t < 16; ++t) {
        float4 q;
        q.x = (4*t+0 == mycol) ? 1.0f : 0.0f;
        q.y = (4*t+1 == mycol) ? 1.0f : 0.0f;
        q.z = (4*t+2 == mycol) ? 1.0f : 0.0f;
        q.w = (4*t+3 == mycol) ? 1.0f : 0.0f;
        ((float4*)orow)[t] = q;
    }
}

extern "C" void kernel_launch(void* const* d_in, const int* in_sizes, int n_in,
                              void* d_out, int out_size, void* d_ws, size_t ws_size,
                              hipStream_t stream) {
    const float* logits = (const float*)d_in[0];
    const float* ptemp  = (const float*)d_in[1];
    float* out = (float*)d_out;
    const int B = in_sizes[0] / 4096;   // 64*64 elements per batch
    const int G = (B + 3) / 4;          // 4 batches (waves) per workgroup
    sinkhorn_perm_kernel<<<G, 256, 0, stream>>>(logits, ptemp, out, B);
}